// Round 8
// baseline (156.623 us; speedup 1.0000x reference)
//
#include <hip/hip_runtime.h>

#define NBINS 12
#define GRID1 2048
#define BLK 256
#define PB 2048              // float4s per block (fast path): 32 KB per array
#define STRIDE (GRID1 * BLK) // generic-path grid stride

typedef float f4 __attribute__((ext_vector_type(4)));

__device__ __forceinline__ float dot4(f4 a, f4 b) {
    return a.x * b.x + a.y * b.y + a.z * b.z + a.w * b.w;
}
__device__ __forceinline__ float sq4(f4 a) {
    return a.x * a.x + a.y * a.y + a.z * a.z + a.w * a.w;
}

// Kernel 1: per-block partials. Fast path: wave-contiguous 2-KB load runs.
// Each wave owns an 8 KB window of x and of t; thread loads 2 CONSECUTIVE
// float4s per array per sub-iter -> successive wave loads walk one DRAM page.
// All 16 loads issued upfront. ws[c*GRID1 + b]: c<12 cross bins, c==12 sumsq.
__global__ __launch_bounds__(BLK, 4) void umse_partial(
    const f4* __restrict__ x4, const f4* __restrict__ t4,
    const int* __restrict__ batch32, float* __restrict__ ws, int nNodes)
{
    __shared__ float cross_lds[NBINS];
    __shared__ float redA[BLK / 64];

    const int tid = threadIdx.x;
    const int lane = tid & 63;
    const int w = tid >> 6;

    if (tid < NBINS) cross_lds[tid] = 0.0f;
    // int32 batch: last slot is a small positive int. int64 viewed as int32:
    // slot nNodes-1 is the high word of a mid-array element -> 0.
    const int is64 = (batch32[nNodes - 1] == 0) ? 1 : 0;
    __syncthreads();

    const int total = nNodes * 16;   // float4 count (D=64 -> 16 f4/node)
    float sumsq = 0.0f;

    if (total == GRID1 * PB) {
        // ---- fast path ----
        const int start = blockIdx.x * PB;          // block's f4 window
        const int wbase = start + w * 512;          // wave's 8 KB window
        const int tbase = wbase + lane * 2;         // thread's 2 consecutive f4
        const int node0 = (start >> 4) + w * 32 + (lane >> 3);

        // graph ids (broadcast within each 8-lane node-group), hoisted early
        int gs[4];
        #pragma unroll
        for (int r = 0; r < 4; ++r) {
            const int n = node0 + r * 8;
            gs[r] = is64 ? batch32[n << 1] : batch32[n];
        }
        // all 16 f4 loads upfront
        f4 xa0[4], xa1[4], tb0[4], tb1[4];
        #pragma unroll
        for (int r = 0; r < 4; ++r) {
            const int i = tbase + r * 128;
            xa0[r] = __builtin_nontemporal_load(x4 + i);
            xa1[r] = __builtin_nontemporal_load(x4 + i + 1);
            tb0[r] = __builtin_nontemporal_load(t4 + i);
            tb1[r] = __builtin_nontemporal_load(t4 + i + 1);
        }
        // consume
        float dots[4];
        #pragma unroll
        for (int r = 0; r < 4; ++r) {
            sumsq += sq4(xa0[r]) + sq4(xa1[r]) + sq4(tb0[r]) + sq4(tb1[r]);
            dots[r] = dot4(xa0[r], tb0[r]) + dot4(xa1[r], tb1[r]);
        }
        // flush: 8-lane node-group reduce + LDS atomic
        #pragma unroll
        for (int r = 0; r < 4; ++r) {
            float p = dots[r];
            p += __shfl_xor(p, 1);
            p += __shfl_xor(p, 2);
            p += __shfl_xor(p, 4);
            if ((lane & 7) == 0) atomicAdd(&cross_lds[gs[r]], p);
        }
    } else {
        // ---- generic fallback: grid-stride, 16-lane groups ----
        const int nIter = total / STRIDE;
        int idx = blockIdx.x * BLK + tid;
        for (int it = 0; it < nIter; ++it, idx += STRIDE) {
            f4 a = __builtin_nontemporal_load(x4 + idx);
            f4 b = __builtin_nontemporal_load(t4 + idx);
            const int n = idx >> 4;
            const int g = is64 ? batch32[n << 1] : batch32[n];
            sumsq += sq4(a) + sq4(b);
            float p = dot4(a, b);
            p += __shfl_xor(p, 1);
            p += __shfl_xor(p, 2);
            p += __shfl_xor(p, 4);
            p += __shfl_xor(p, 8);
            if ((lane & 15) == 0) atomicAdd(&cross_lds[g], p);
        }
        if (idx < total) {   // ragged tail
            f4 a = x4[idx];
            f4 b = t4[idx];
            const int n = idx >> 4;
            const int g = is64 ? batch32[n << 1] : batch32[n];
            sumsq += sq4(a) + sq4(b);
            atomicAdd(&cross_lds[g], dot4(a, b));
        }
    }

    // Block reduction of sumsq.
    for (int m = 32; m; m >>= 1) sumsq += __shfl_xor(sumsq, m);
    if (lane == 0) redA[tid >> 6] = sumsq;
    __syncthreads();   // also orders the LDS atomics above

    if (tid < NBINS) ws[tid * GRID1 + blockIdx.x] = cross_lds[tid];
    if (tid == NBINS) {
        float s = 0.0f;
        #pragma unroll
        for (int k = 0; k < BLK / 64; ++k) s += redA[k];
        ws[NBINS * GRID1 + blockIdx.x] = s;
    }
}

// Kernel 2: 13 waves, wave w reduces column w (contiguous, coalesced), fp64.
__global__ __launch_bounds__(832) void umse_final(
    const float* __restrict__ ws, float* __restrict__ out)
{
    __shared__ double cols[13];
    const int tid = threadIdx.x;
    const int w = tid >> 6, lane = tid & 63;

    double s = 0.0;
    for (int b = lane; b < GRID1; b += 64) s += (double)ws[w * GRID1 + b];
    for (int m = 32; m; m >>= 1) s += __shfl_xor(s, m);
    if (lane == 0) cols[w] = s;
    __syncthreads();

    if (tid == 0) {
        double acc = 0.0;
        for (int g = 0; g < NBINS; ++g) acc += fabs(cols[g]);
        out[0] = (float)(cols[12] - 2.0 * acc);
    }
}

extern "C" void kernel_launch(void* const* d_in, const int* in_sizes, int n_in,
                              void* d_out, int out_size, void* d_ws, size_t ws_size,
                              hipStream_t stream)
{
    const float* x = (const float*)d_in[0];
    const float* t = (const float*)d_in[1];
    const int* batch = (const int*)d_in[2];
    const int nNodes = in_sizes[2];   // N = 262144
    float* ws = (float*)d_ws;
    float* out = (float*)d_out;

    umse_partial<<<GRID1, BLK, 0, stream>>>(
        (const f4*)x, (const f4*)t, batch, ws, nNodes);
    umse_final<<<1, 832, 0, stream>>>(ws, out);
}